// Round 6
// baseline (1262.828 us; speedup 1.0000x reference)
//
#include <hip/hip_runtime.h>
#include <hip/hip_bf16.h>

#define LSEQ   2048
#define NHEAD  16
#define NCHUNK 32
#define WKV_NB 32
#define SSD_NB 1024   // NBATCH*NCHUNK*NHEAD

// workspace layout (floats)
#define WS_CS 0u          // chunk states -> (after scan) entering states, (sid,p,n)
#define WS_YD 4194304u    // Y_diag f32, (b,l,h,p) == output layout
#define WS_CA 8388608u    // per-chunk inclusive cumsum of A, (sid,64)

__device__ __forceinline__ float rl(float x, int l) {
    return __int_as_float(__builtin_amdgcn_readlane(__float_as_int(x), l));
}

// full-wave (64-lane) sum via DPP; result valid in lane 63 (others partial)
__device__ __forceinline__ float wave_red(float x) {
    x += __int_as_float(__builtin_amdgcn_update_dpp(0, __float_as_int(x), 0x111, 0xf, 0xf, true)); // row_shr:1
    x += __int_as_float(__builtin_amdgcn_update_dpp(0, __float_as_int(x), 0x112, 0xf, 0xf, true)); // row_shr:2
    x += __int_as_float(__builtin_amdgcn_update_dpp(0, __float_as_int(x), 0x114, 0xf, 0xf, true)); // row_shr:4
    x += __int_as_float(__builtin_amdgcn_update_dpp(0, __float_as_int(x), 0x118, 0xf, 0xf, true)); // row_shr:8
    x += __int_as_float(__builtin_amdgcn_update_dpp(0, __float_as_int(x), 0x142, 0xa, 0xf, true)); // row_bcast:15
    x += __int_as_float(__builtin_amdgcn_update_dpp(0, __float_as_int(x), 0x143, 0xc, 0xf, true)); // row_bcast:31
    return x;
}

// padded per-s scalar-block sizes/offsets in the SC exchange region (128 floats)
__device__ constexpr int SBLK[8]  = {8, 16, 20, 20, 20, 20, 16, 8};
__device__ constexpr int SOFF[8]  = {0, 8, 24, 44, 64, 84, 104, 120};
__device__ constexpr int SBLK4[8] = {2, 4, 5, 5, 5, 5, 4, 2};
__device__ constexpr int XBASE[8] = {0, 8, 15, 21, 26, 30, 33, 35};

#define GETF(B, I) ((I) % 4 == 0 ? (B)[(I) / 4].x : (I) % 4 == 1 ? (B)[(I) / 4].y \
                  : (I) % 4 == 2 ? (B)[(I) / 4].z : (B)[(I) / 4].w)

// 120 independent dots (36 U + 84 G), contiguous range [30*WSEL, 30*WSEL+30)
// per wave; all indices compile-time after full unroll.
template <int WSEL>
__device__ __forceinline__ void dots_phase(const float (&u)[8], const float (&K)[8],
                                           const float (&D)[8], const float (&Ch)[8],
                                           float* sc, int lane)
{
    float res[30];
    int aoff[30];
    int nres = 0, d = 0;
    #pragma unroll
    for (int s = 0; s < 8; s++) {
        const float Dm1 = (s == 0) ? 1.f : D[s - 1];
        #pragma unroll
        for (int m = s; m < 8; m++) {                 // U_{s,m} = u_s . k_m
            if (d >= 30 * WSEL && d < 30 * WSEL + 30) {
                res[nres]  = wave_red(u[s] * K[m]);
                aoff[nres] = SOFF[s] + (m - s);
                nres++;
            }
            d++;
        }
        #pragma unroll
        for (int j = 0; j < s; j++) {                 // G_{j,s,m} = (D_{s-1} c^_j) . k_m
            #pragma unroll
            for (int m = s; m < 8; m++) {
                if (d >= 30 * WSEL && d < 30 * WSEL + 30) {
                    res[nres]  = wave_red(Dm1 * Ch[j] * K[m]);
                    aoff[nres] = SOFF[s] + (8 - s) + j * (8 - s) + (m - s);
                    nres++;
                }
                d++;
            }
        }
    }
    if (lane == 63) {
        #pragma unroll
        for (int q2 = 0; q2 < 30; q2++) sc[aoff[q2]] = res[q2];
    }
}

// ---------------------------------------------------------------------------
// Fused kernel: blocks [0,32) = WKV (4 waves, 8-step WY chunk, 2 barriers and
//               one batched cross-lane dot phase per chunk),
//               blocks [32,1056) = SSD intra-chunk (256 threads)
// ---------------------------------------------------------------------------
__global__ __launch_bounds__(256)
void k_fused(const float* __restrict__ X, const float* __restrict__ A,
             const float* __restrict__ Bm, const float* __restrict__ Cm,
             const float* __restrict__ rg, const float* __restrict__ kg,
             const float* __restrict__ vg, const float* __restrict__ wg,
             const float* __restrict__ bg, float* __restrict__ ws,
             float* __restrict__ out)
{
    __shared__ float Bs[64][68];
    __shared__ float CsGL[64][68];
    __shared__ float Xs[64][64];
    __shared__ float cA[64], decL[64];

    const int t = threadIdx.x;

    if (blockIdx.x < WKV_NB) {
        // ===== WKV: lane = row i; wave w4 owns state columns [16w4,16w4+16) =====
        const int lane = t & 63;
        const int w4   = __builtin_amdgcn_readfirstlane(t) >> 6;  // uniform wave id
        const int jb   = w4 << 4;

        float* Pl = &Bs[0][0];          // q-exchange: [8 m][4 wave][64 lane]
        float* SC = &Bs[0][0] + 2048;   // 128 scalar dots

        const int bh = blockIdx.x;
        const int b  = bh >> 4, h = bh & 15;
        const size_t base = (size_t)bh * LSEQ * 64 + lane;
        const float* pr = rg + base;
        const float* pk = kg + base;
        const float* pv = vg + base;
        const float* pw = wg + base;
        const float* pb = bg + base;
        float* pout = out + ((size_t)b * LSEQ * NHEAD + h) * 64 + lane;

        float st[16];                    // S[lane][jb+c] (true, unnormalized)
        #pragma unroll
        for (int c = 0; c < 16; c++) st[c] = 0.f;

        // STATIC double-buffer register sets (no runtime indexing!)
        float R0[8], K0[8], V0[8], W0[8], B0[8];
        float R1[8], K1[8], V1[8], W1[8], B1[8];

        auto pref = [&](float (&R)[8], float (&K)[8], float (&V)[8],
                        float (&W)[8], float (&Bb)[8], int tb) {
            #pragma unroll
            for (int m = 0; m < 8; m++) {
                size_t o = (size_t)(tb + m) * 64;
                R[m] = pr[o]; K[m] = pk[o]; V[m] = pv[o]; W[m] = pw[o]; Bb[m] = pb[o];
            }
        };

        // one 8-step WY chunk (exact expansion of the verified R3 block form):
        //   q_m = S k_m ; u_m = v_m - D_{m-1} q_m
        //   x_{s,m} = U_{s,m} - sum_{j<s} x_{j,s} G_{j,s,m}   (scalar triangle)
        //   delta_s = u_s - sum_{j<s} x_{j,s} (D_{s-1} c^_j)
        //   y_m = r_m D_m (q_m + sum_{s<=m} x_{s,m} c^_s)
        //   S  += sum_s c^_s delta_s^T ; S *= D_7
        auto proc = [&](float (&R)[8], float (&K)[8], float (&V)[8],
                        float (&W)[8], float (&Bb)[8], int tb) {
            float D[8], Ch[8];
            {
                float d = 1.f, id = 1.f;
                #pragma unroll
                for (int m = 0; m < 8; m++) {
                    d  *= W[m];
                    id *= __builtin_amdgcn_rcpf(W[m]);
                    D[m]  = d;
                    Ch[m] = Bb[m] * K[m] * id;
                }
            }

            // Q partials over own 16 columns
            float p[8];
            #pragma unroll
            for (int m = 0; m < 8; m++) {
                float a0 = 0.f, a1 = 0.f, a2 = 0.f, a3 = 0.f;
                #pragma unroll
                for (int c = 0; c < 16; c += 4) {
                    a0 += st[c + 0] * rl(K[m], jb + c + 0);
                    a1 += st[c + 1] * rl(K[m], jb + c + 1);
                    a2 += st[c + 2] * rl(K[m], jb + c + 2);
                    a3 += st[c + 3] * rl(K[m], jb + c + 3);
                }
                p[m] = (a0 + a1) + (a2 + a3);
            }
            #pragma unroll
            for (int m = 0; m < 8; m++) Pl[m * 256 + (w4 << 6) + lane] = p[m];
            asm volatile("s_waitcnt lgkmcnt(0)" ::: "memory");
            __builtin_amdgcn_s_barrier();
            asm volatile("" ::: "memory");

            float q[8], u[8];
            #pragma unroll
            for (int m = 0; m < 8; m++) {
                q[m] = (Pl[m * 256 + lane] + Pl[m * 256 + 64 + lane]) +
                       (Pl[m * 256 + 128 + lane] + Pl[m * 256 + 192 + lane]);
                u[m] = V[m] - ((m == 0) ? 1.f : D[m - 1]) * q[m];
            }

            // batched independent cross-lane dots, 30 per wave
            if      (w4 == 0) dots_phase<0>(u, K, D, Ch, SC, lane);
            else if (w4 == 1) dots_phase<1>(u, K, D, Ch, SC, lane);
            else if (w4 == 2) dots_phase<2>(u, K, D, Ch, SC, lane);
            else              dots_phase<3>(u, K, D, Ch, SC, lane);
            asm volatile("s_waitcnt lgkmcnt(0)" ::: "memory");
            __builtin_amdgcn_s_barrier();
            asm volatile("" ::: "memory");

            // scalar triangle (uniform, redundant in all waves) + per-lane delta
            float xx[36], dl[8];
            #pragma unroll
            for (int s = 0; s < 8; s++) {
                float4 blk[5];
                #pragma unroll
                for (int b4 = 0; b4 < SBLK4[s]; b4++)
                    blk[b4] = *(const float4*)&SC[SOFF[s] + 4 * b4];
                const float Dm1 = (s == 0) ? 1.f : D[s - 1];
                float dv = u[s];
                #pragma unroll
                for (int j = 0; j < s; j++)
                    dv -= xx[XBASE[j] + (s - j)] * (Dm1 * Ch[j]);
                dl[s] = dv;
                #pragma unroll
                for (int m = s; m < 8; m++) {
                    float acc = GETF(blk, m - s);                       // U_{s,m}
                    #pragma unroll
                    for (int j = 0; j < s; j++)
                        acc -= xx[XBASE[j] + (s - j)] *
                               GETF(blk, (8 - s) + j * (8 - s) + (m - s)); // G
                    xx[XBASE[s] + (m - s)] = acc;
                }
            }

            // y (redundant; wave m>>1 stores its 2 steps)
            #pragma unroll
            for (int m = 0; m < 8; m++) {
                float acc = q[m];
                #pragma unroll
                for (int s = 0; s <= m; s++) acc += xx[XBASE[s] + (m - s)] * Ch[s];
                if (w4 == (m >> 1))
                    pout[(size_t)(tb + m) * (NHEAD * 64)] = R[m] * (D[m] * acc);
            }

            // rank-8 state update on own 16 columns, then chunk decay
            #pragma unroll
            for (int s = 0; s < 8; s++) {
                float cs = Ch[s];
                #pragma unroll
                for (int c = 0; c < 16; c++) st[c] += cs * rl(dl[s], jb + c);
            }
            #pragma unroll
            for (int c = 0; c < 16; c++) st[c] *= D[7];
        };

        pref(R0, K0, V0, W0, B0, 0);
        pref(R1, K1, V1, W1, B1, 8);
        for (int t0 = 0; t0 < LSEQ; t0 += 16) {
            proc(R0, K0, V0, W0, B0, t0);
            if (t0 + 16 < LSEQ) pref(R0, K0, V0, W0, B0, t0 + 16);
            proc(R1, K1, V1, W1, B1, t0 + 8);
            if (t0 + 24 < LSEQ) pref(R1, K1, V1, W1, B1, t0 + 24);
        }
        return;
    }

    // ================= SSD intra-chunk =================
    const int sid = blockIdx.x - WKV_NB;
    const int b = sid >> 9;
    const int c = (sid >> 4) & 31;
    const int h = sid & 15;
    const size_t rowbase = ((size_t)(b * LSEQ + c * 64) * NHEAD + h) * 64;
    const int rstride = NHEAD * 64;   // 1024

    #pragma unroll
    for (int i = 0; i < 4; i++) {
        int fl = t + 256 * i; int row = fl >> 4; int c4 = fl & 15;
        size_t go = rowbase + (size_t)row * rstride;
        float4 xv = ((const float4*)(X  + go))[c4];
        float4 bv = ((const float4*)(Bm + go))[c4];
        float4 cv = ((const float4*)(Cm + go))[c4];
        *(float4*)&Xs[row][c4 * 4]   = xv;
        *(float4*)&Bs[row][c4 * 4]   = bv;
        *(float4*)&CsGL[row][c4 * 4] = cv;
    }
    if (t < 64) {
        float a = A[(size_t)(b * LSEQ + c * 64 + t) * NHEAD + h];
        float s = a;
        #pragma unroll
        for (int off = 1; off < 64; off <<= 1) {
            float nv = __shfl_up(s, off, 64);
            if (t >= off) s += nv;
        }
        cA[t] = s;
        ws[WS_CA + (size_t)sid * 64 + t] = s;
        float tot = __shfl(s, 63, 64);
        decL[t] = expf(tot - s);
    }
    __syncthreads();

    const int l = t >> 2;
    const int q = t & 3;

    // G[l][s] = <C_l, B_s> * exp(cA[l]-cA[s]) for s<=l else 0   (s = q + 4*si)
    float g[16];
    {
        float acc[16];
        #pragma unroll
        for (int si = 0; si < 16; si++) acc[si] = 0.f;
        #pragma unroll
        for (int n4 = 0; n4 < 16; n4++) {
            float4 cv = *(const float4*)&CsGL[l][n4 * 4];
            #pragma unroll
            for (int si = 0; si < 16; si++) {
                float4 bv = *(const float4*)&Bs[q + 4 * si][n4 * 4];
                acc[si] += cv.x * bv.x + cv.y * bv.y + cv.z * bv.z + cv.w * bv.w;
            }
        }
        float cl = cA[l];
        #pragma unroll
        for (int si = 0; si < 16; si++) {
            int s = q + 4 * si;
            g[si] = (s <= l) ? acc[si] * expf(cl - cA[s]) : 0.f;
        }
    }
    __syncthreads();
    #pragma unroll
    for (int si = 0; si < 16; si++) CsGL[l][q + 4 * si] = g[si];
    __syncthreads();

    // Y_diag[l][p] = sum_s GL[l][s] * X[s][p]
    {
        const int pb = q * 16;
        float4 acc[4];
        #pragma unroll
        for (int i = 0; i < 4; i++) acc[i] = make_float4(0.f, 0.f, 0.f, 0.f);
        for (int s = 0; s < 64; s++) {
            float gv = CsGL[l][s];
            #pragma unroll
            for (int i = 0; i < 4; i++) {
                float4 xv = *(const float4*)&Xs[s][pb + 4 * i];
                acc[i].x += gv * xv.x; acc[i].y += gv * xv.y;
                acc[i].z += gv * xv.z; acc[i].w += gv * xv.w;
            }
        }
        size_t o = rowbase + (size_t)l * rstride + pb;
        float* yd = ws + WS_YD;
        #pragma unroll
        for (int i = 0; i < 4; i++) ((float4*)(yd + o))[i] = acc[i];
    }

    // chunk_states[p][n] = sum_l decL[l] * X[l][p] * B[l][n]
    {
        const int p  = l;
        const int nb = q * 16;
        float4 acc[4];
        #pragma unroll
        for (int i = 0; i < 4; i++) acc[i] = make_float4(0.f, 0.f, 0.f, 0.f);
        for (int l2 = 0; l2 < 64; l2++) {
            float cf = decL[l2] * Xs[l2][p];
            #pragma unroll
            for (int i = 0; i < 4; i++) {
                float4 bv = *(const float4*)&Bs[l2][nb + 4 * i];
                acc[i].x += cf * bv.x; acc[i].y += cf * bv.y;
                acc[i].z += cf * bv.z; acc[i].w += cf * bv.w;
            }
        }
        float* cs = ws + WS_CS + (size_t)sid * 4096 + (size_t)p * 64 + nb;
        #pragma unroll
        for (int i = 0; i < 4; i++) ((float4*)cs)[i] = acc[i];
    }
}

// ---------------------------------------------------------------------------
// K2: inter-chunk scan per (b,h): overwrite cs_c with state ENTERING chunk c
// ---------------------------------------------------------------------------
__global__ __launch_bounds__(256)
void k_scan(float* __restrict__ ws)
{
    const int t = threadIdx.x;
    const int b = blockIdx.x >> 4;
    const int h = blockIdx.x & 15;
    float prev[16];
    #pragma unroll
    for (int qq = 0; qq < 16; qq++) prev[qq] = 0.f;
    for (int c = 0; c < NCHUNK; c++) {
        const int sid = b * 512 + c * 16 + h;
        float dec = expf(ws[WS_CA + (size_t)sid * 64 + 63]);
        float* cs = ws + WS_CS + (size_t)sid * 4096;
        float tmp[16];
        #pragma unroll
        for (int qq = 0; qq < 16; qq++) tmp[qq] = cs[t + 256 * qq];
        #pragma unroll
        for (int qq = 0; qq < 16; qq++) cs[t + 256 * qq] = prev[qq];
        #pragma unroll
        for (int qq = 0; qq < 16; qq++) prev[qq] = prev[qq] * dec + tmp[qq];
    }
}

// ---------------------------------------------------------------------------
// K3: out = Y_diag + exp(cumA[l]) * C_l . state^T + out(=wkv)    (all f32)
// ---------------------------------------------------------------------------
__global__ __launch_bounds__(256)
void k_yoff(const float* __restrict__ Cm, const float* __restrict__ ws,
            float* __restrict__ out)
{
    __shared__ float Cs[64][68];
    __shared__ float ST[64][68];   // ST[n][p] = state[p][n]
    __shared__ float dout[64];
    const int t = threadIdx.x;
    const int sid = blockIdx.x;
    const int b = sid >> 9;
    const int c = (sid >> 4) & 31;
    const int h = sid & 15;
    const size_t rowbase = ((size_t)(b * LSEQ + c * 64) * NHEAD + h) * 64;
    const int rstride = NHEAD * 64;

    #pragma unroll
    for (int i = 0; i < 4; i++) {
        int fl = t + 256 * i; int row = fl >> 4; int c4 = fl & 15;
        float4 cv = ((const float4*)(Cm + rowbase + (size_t)row * rstride))[c4];
        *(float4*)&Cs[row][c4 * 4] = cv;
        float4 sv = ((const float4*)(ws + WS_CS + (size_t)sid * 4096 + (size_t)row * 64))[c4];
        ST[c4 * 4 + 0][row] = sv.x;
        ST[c4 * 4 + 1][row] = sv.y;
        ST[c4 * 4 + 2][row] = sv.z;
        ST[c4 * 4 + 3][row] = sv.w;
    }
    if (t < 64) dout[t] = expf(ws[WS_CA + (size_t)sid * 64 + t]);
    __syncthreads();

    const int l  = t >> 2;
    const int pb = (t & 3) * 16;
    float4 acc[4];
    #pragma unroll
    for (int i = 0; i < 4; i++) acc[i] = make_float4(0.f, 0.f, 0.f, 0.f);
    for (int n = 0; n < 64; n++) {
        float cv = Cs[l][n];
        #pragma unroll
        for (int i = 0; i < 4; i++) {
            float4 sv = *(const float4*)&ST[n][pb + 4 * i];
            acc[i].x += cv * sv.x; acc[i].y += cv * sv.y;
            acc[i].z += cv * sv.z; acc[i].w += cv * sv.w;
        }
    }
    const float sc = dout[l];
    const size_t o = rowbase + (size_t)l * rstride + pb;
    #pragma unroll
    for (int i = 0; i < 4; i++) {
        float4 yd = ((const float4*)(ws + WS_YD + o))[i];
        float4 yw = ((const float4*)(out + o))[i];
        float4 res;
        res.x = yd.x + sc * acc[i].x + yw.x;
        res.y = yd.y + sc * acc[i].y + yw.y;
        res.z = yd.z + sc * acc[i].z + yw.z;
        res.w = yd.w + sc * acc[i].w + yw.w;
        ((float4*)(out + o))[i] = res;
    }
}

extern "C" void kernel_launch(void* const* d_in, const int* in_sizes, int n_in,
                              void* d_out, int out_size, void* d_ws, size_t ws_size,
                              hipStream_t stream)
{
    const float* X  = (const float*)d_in[0];
    const float* A  = (const float*)d_in[1];
    const float* Bm = (const float*)d_in[2];
    const float* Cm = (const float*)d_in[3];
    const float* r  = (const float*)d_in[4];
    const float* k  = (const float*)d_in[5];
    const float* v  = (const float*)d_in[6];
    const float* w  = (const float*)d_in[7];
    const float* bo = (const float*)d_in[8];
    float* ws = (float*)d_ws;
    float* out = (float*)d_out;

    hipLaunchKernelGGL(k_fused, dim3(WKV_NB + SSD_NB), dim3(256), 0, stream,
                       X, A, Bm, Cm, r, k, v, w, bo, ws, out);
    hipLaunchKernelGGL(k_scan, dim3(32),     dim3(256), 0, stream, ws);
    hipLaunchKernelGGL(k_yoff, dim3(SSD_NB), dim3(256), 0, stream, Cm, ws, out);
}

// Round 7
// 1010.438 us; speedup vs baseline: 1.2498x; 1.2498x over previous
//
#include <hip/hip_runtime.h>
#include <hip/hip_bf16.h>

#define LSEQ   2048
#define NHEAD  16
#define NCHUNK 32
#define WKV_NB 32
#define SSD_NB 1024   // NBATCH*NCHUNK*NHEAD

// workspace layout (floats)
#define WS_CS 0u          // chunk states -> (after scan) entering states, (sid,p,n)
#define WS_YD 4194304u    // Y_diag f32, (b,l,h,p) == output layout
#define WS_CA 8388608u    // per-chunk inclusive cumsum of A, (sid,64)

__device__ __forceinline__ float rl(float x, int l) {
    return __int_as_float(__builtin_amdgcn_readlane(__float_as_int(x), l));
}

// full-wave (64-lane) sum via DPP, broadcast through SGPR (lane 63)
__device__ __forceinline__ float wave_sum(float x) {
    x += __int_as_float(__builtin_amdgcn_update_dpp(0, __float_as_int(x), 0x111, 0xf, 0xf, true)); // row_shr:1
    x += __int_as_float(__builtin_amdgcn_update_dpp(0, __float_as_int(x), 0x112, 0xf, 0xf, true)); // row_shr:2
    x += __int_as_float(__builtin_amdgcn_update_dpp(0, __float_as_int(x), 0x114, 0xf, 0xf, true)); // row_shr:4
    x += __int_as_float(__builtin_amdgcn_update_dpp(0, __float_as_int(x), 0x118, 0xf, 0xf, true)); // row_shr:8
    x += __int_as_float(__builtin_amdgcn_update_dpp(0, __float_as_int(x), 0x142, 0xa, 0xf, true)); // row_bcast:15
    x += __int_as_float(__builtin_amdgcn_update_dpp(0, __float_as_int(x), 0x143, 0xc, 0xf, true)); // row_bcast:31
    return __int_as_float(__builtin_amdgcn_readlane(__float_as_int(x), 63));
}

// ---------------------------------------------------------------------------
// Fused kernel: blocks [0,32) = WKV (4 waves, column-split state, one barrier
//               per step; chain = read->delta->rl->fused FMA->write; y analytic),
//               blocks [32,1056) = SSD intra-chunk (256 threads)
// ---------------------------------------------------------------------------
__global__ __launch_bounds__(256)
void k_fused(const float* __restrict__ X, const float* __restrict__ A,
             const float* __restrict__ Bm, const float* __restrict__ Cm,
             const float* __restrict__ rg, const float* __restrict__ kg,
             const float* __restrict__ vg, const float* __restrict__ wg,
             const float* __restrict__ bg, float* __restrict__ ws,
             float* __restrict__ out)
{
    __shared__ float Bs[64][68];
    __shared__ float CsGL[64][68];
    __shared__ float Xs[64][64];
    __shared__ float cA[64], decL[64];

    const int t = threadIdx.x;

    if (blockIdx.x < WKV_NB) {
        // ===== WKV: lane = state row; wave w4 owns columns [16w4,16w4+16) =====
        const int lane = t & 63;
        const int w4   = __builtin_amdgcn_readfirstlane(t) >> 6;  // uniform wave id
        const int jb   = w4 << 4;

        float* pEx = &CsGL[0][0];        // [2 parity][4 wave][64 lane] b32, conflict-free

        const int bh = blockIdx.x;
        const int b  = bh >> 4, h = bh & 15;
        const size_t base = (size_t)bh * LSEQ * 64 + lane;
        const float* pr = rg + base;
        const float* pk = kg + base;
        const float* pv = vg + base;
        const float* pw = wg + base;
        const float* pb = bg + base;
        float* pout = out + ((size_t)b * LSEQ * NHEAD + h) * 64 + lane;

        float st[16];                    // S[lane][jb+c] / alpha[lane]
        #pragma unroll
        for (int c = 0; c < 16; c++) st[c] = 0.f;
        float alpha = 1.f, ialpha = 1.f;
        float p = 0.f;                   // carried own-col dot: st . k_t
        float ksA[16], ksB[16];          // k slices, parity by step

        // STATIC double-buffer register sets (no runtime indexing!)
        float R0[8], K0[8], V0[8], W0[8], B0[8];
        float R1[8], K1[8], V1[8], W1[8], B1[8];

        auto pref = [&](float (&R)[8], float (&K)[8], float (&V)[8],
                        float (&W)[8], float (&Bb)[8], int tb) {
            #pragma unroll
            for (int m = 0; m < 8; m++) {
                size_t o = (size_t)(tb + m) * 64;
                R[m] = pr[o]; K[m] = pk[o]; V[m] = pv[o]; W[m] = pw[o]; Bb[m] = pb[o];
            }
        };

        // per step m:
        //   publish p = st_{t-1}.k_t (own cols); barrier; q = sum of 4 partials
        //   u = alpha*q; delta = v - u (per lane)
        //   y = r*(w*u + (b*k)*tau), tau = wave_sum(delta*k_t)    [off-chain]
        //   st[c] += coef*delta[jb+c]; p' += st[c]*k_{t+1}[jb+c]  [fused 32 FMA]
        //   prefetch k_{t+2} slices via readlane                  [off-chain]
        auto proc = [&](float (&R)[8], float (&K)[8], float (&V)[8],
                        float (&W)[8], float (&Bb)[8], int tb,
                        float kn0, float kn1) {
            float iW[8];
            #pragma unroll
            for (int m = 0; m < 8; m++) iW[m] = __builtin_amdgcn_rcpf(W[m]);

            #pragma unroll
            for (int m = 0; m < 8; m++) {
                float* pbuf = pEx + ((m & 1) << 8);
                pbuf[(w4 << 6) + lane] = p;
                asm volatile("s_waitcnt lgkmcnt(0)" ::: "memory");
                __builtin_amdgcn_s_barrier();
                asm volatile("" ::: "memory");

                float q = (pbuf[lane] + pbuf[64 + lane]) +
                          (pbuf[128 + lane] + pbuf[192 + lane]);
                float u  = alpha * q;                 // (S_{t-1} k_t)[lane]
                float dl = V[m] - u;                  // delta[lane]

                // y analytic (off the recurrence chain); wave m&3 stores
                float tau = wave_sum(dl * K[m]);
                float ck  = Bb[m] * K[m];
                if (w4 == (m & 3))
                    pout[(size_t)(tb + m) * (NHEAD * 64)] =
                        R[m] * (W[m] * u + ck * tau);

                alpha  *= W[m];
                ialpha *= iW[m];
                float coef = ck * ialpha;             // S = alpha*st invariant

                // kc holds k_{tb+m+1} slices; kx will get k_{tb+m+2}
                float* kc = (m & 1) ? ksA : ksB;
                float* kx = (m & 1) ? ksB : ksA;
                float knn = (m < 6) ? K[m + 2] : ((m == 6) ? kn0 : kn1);

                // fused on-chain: rl(delta) + state update + next-dot partial
                float p0 = 0.f, p1 = 0.f, p2 = 0.f, p3 = 0.f;
                #pragma unroll
                for (int c = 0; c < 16; c += 4) {
                    float d0 = rl(dl, jb + c + 0), d1 = rl(dl, jb + c + 1);
                    float d2 = rl(dl, jb + c + 2), d3 = rl(dl, jb + c + 3);
                    st[c + 0] += coef * d0; p0 += st[c + 0] * kc[c + 0];
                    st[c + 1] += coef * d1; p1 += st[c + 1] * kc[c + 1];
                    st[c + 2] += coef * d2; p2 += st[c + 2] * kc[c + 2];
                    st[c + 3] += coef * d3; p3 += st[c + 3] * kc[c + 3];
                }
                p = (p0 + p1) + (p2 + p3);

                // off-chain: prefetch k_{t+2} slices
                #pragma unroll
                for (int c = 0; c < 16; c++) kx[c] = rl(knn, jb + c);
            }

            // fold alpha back into st and carried dot (alpha >= 0.9^8 = 0.43)
            #pragma unroll
            for (int c = 0; c < 16; c++) st[c] *= alpha;
            p *= alpha;
            alpha = 1.f; ialpha = 1.f;
        };

        pref(R0, K0, V0, W0, B0, 0);
        pref(R1, K1, V1, W1, B1, 8);
        #pragma unroll
        for (int c = 0; c < 16; c++) ksB[c] = rl(K0[1], jb + c);  // k_1 slices

        for (int t0 = 0; t0 < LSEQ; t0 += 16) {
            proc(R0, K0, V0, W0, B0, t0, K1[0], K1[1]);
            if (t0 + 16 < LSEQ) pref(R0, K0, V0, W0, B0, t0 + 16);
            proc(R1, K1, V1, W1, B1, t0 + 8, K0[0], K0[1]);
            if (t0 + 16 < LSEQ) pref(R1, K1, V1, W1, B1, t0 + 24);
        }
        return;
    }

    // ================= SSD intra-chunk =================
    const int sid = blockIdx.x - WKV_NB;
    const int b = sid >> 9;
    const int c = (sid >> 4) & 31;
    const int h = sid & 15;
    const size_t rowbase = ((size_t)(b * LSEQ + c * 64) * NHEAD + h) * 64;
    const int rstride = NHEAD * 64;   // 1024

    #pragma unroll
    for (int i = 0; i < 4; i++) {
        int fl = t + 256 * i; int row = fl >> 4; int c4 = fl & 15;
        size_t go = rowbase + (size_t)row * rstride;
        float4 xv = ((const float4*)(X  + go))[c4];
        float4 bv = ((const float4*)(Bm + go))[c4];
        float4 cv = ((const float4*)(Cm + go))[c4];
        *(float4*)&Xs[row][c4 * 4]   = xv;
        *(float4*)&Bs[row][c4 * 4]   = bv;
        *(float4*)&CsGL[row][c4 * 4] = cv;
    }
    if (t < 64) {
        float a = A[(size_t)(b * LSEQ + c * 64 + t) * NHEAD + h];
        float s = a;
        #pragma unroll
        for (int off = 1; off < 64; off <<= 1) {
            float nv = __shfl_up(s, off, 64);
            if (t >= off) s += nv;
        }
        cA[t] = s;
        ws[WS_CA + (size_t)sid * 64 + t] = s;
        float tot = __shfl(s, 63, 64);
        decL[t] = expf(tot - s);
    }
    __syncthreads();

    const int l = t >> 2;
    const int q = t & 3;

    // G[l][s] = <C_l, B_s> * exp(cA[l]-cA[s]) for s<=l else 0   (s = q + 4*si)
    float g[16];
    {
        float acc[16];
        #pragma unroll
        for (int si = 0; si < 16; si++) acc[si] = 0.f;
        #pragma unroll
        for (int n4 = 0; n4 < 16; n4++) {
            float4 cv = *(const float4*)&CsGL[l][n4 * 4];
            #pragma unroll
            for (int si = 0; si < 16; si++) {
                float4 bv = *(const float4*)&Bs[q + 4 * si][n4 * 4];
                acc[si] += cv.x * bv.x + cv.y * bv.y + cv.z * bv.z + cv.w * bv.w;
            }
        }
        float cl = cA[l];
        #pragma unroll
        for (int si = 0; si < 16; si++) {
            int s = q + 4 * si;
            g[si] = (s <= l) ? acc[si] * expf(cl - cA[s]) : 0.f;
        }
    }
    __syncthreads();
    #pragma unroll
    for (int si = 0; si < 16; si++) CsGL[l][q + 4 * si] = g[si];
    __syncthreads();

    // Y_diag[l][p] = sum_s GL[l][s] * X[s][p]
    {
        const int pb = q * 16;
        float4 acc[4];
        #pragma unroll
        for (int i = 0; i < 4; i++) acc[i] = make_float4(0.f, 0.f, 0.f, 0.f);
        for (int s = 0; s < 64; s++) {
            float gv = CsGL[l][s];
            #pragma unroll
            for (int i = 0; i < 4; i++) {
                float4 xv = *(const float4*)&Xs[s][pb + 4 * i];
                acc[i].x += gv * xv.x; acc[i].y += gv * xv.y;
                acc[i].z += gv * xv.z; acc[i].w += gv * xv.w;
            }
        }
        size_t o = rowbase + (size_t)l * rstride + pb;
        float* yd = ws + WS_YD;
        #pragma unroll
        for (int i = 0; i < 4; i++) ((float4*)(yd + o))[i] = acc[i];
    }

    // chunk_states[p][n] = sum_l decL[l] * X[l][p] * B[l][n]
    {
        const int p  = l;
        const int nb = q * 16;
        float4 acc[4];
        #pragma unroll
        for (int i = 0; i < 4; i++) acc[i] = make_float4(0.f, 0.f, 0.f, 0.f);
        for (int l2 = 0; l2 < 64; l2++) {
            float cf = decL[l2] * Xs[l2][p];
            #pragma unroll
            for (int i = 0; i < 4; i++) {
                float4 bv = *(const float4*)&Bs[l2][nb + 4 * i];
                acc[i].x += cf * bv.x; acc[i].y += cf * bv.y;
                acc[i].z += cf * bv.z; acc[i].w += cf * bv.w;
            }
        }
        float* cs = ws + WS_CS + (size_t)sid * 4096 + (size_t)p * 64 + nb;
        #pragma unroll
        for (int i = 0; i < 4; i++) ((float4*)cs)[i] = acc[i];
    }
}

// ---------------------------------------------------------------------------
// K2: inter-chunk scan per (b,h): overwrite cs_c with state ENTERING chunk c
// ---------------------------------------------------------------------------
__global__ __launch_bounds__(256)
void k_scan(float* __restrict__ ws)
{
    const int t = threadIdx.x;
    const int b = blockIdx.x >> 4;
    const int h = blockIdx.x & 15;
    float prev[16];
    #pragma unroll
    for (int qq = 0; qq < 16; qq++) prev[qq] = 0.f;
    for (int c = 0; c < NCHUNK; c++) {
        const int sid = b * 512 + c * 16 + h;
        float dec = expf(ws[WS_CA + (size_t)sid * 64 + 63]);
        float* cs = ws + WS_CS + (size_t)sid * 4096;
        float tmp[16];
        #pragma unroll
        for (int qq = 0; qq < 16; qq++) tmp[qq] = cs[t + 256 * qq];
        #pragma unroll
        for (int qq = 0; qq < 16; qq++) cs[t + 256 * qq] = prev[qq];
        #pragma unroll
        for (int qq = 0; qq < 16; qq++) prev[qq] = prev[qq] * dec + tmp[qq];
    }
}

// ---------------------------------------------------------------------------
// K3: out = Y_diag + exp(cumA[l]) * C_l . state^T + out(=wkv)    (all f32)
// ---------------------------------------------------------------------------
__global__ __launch_bounds__(256)
void k_yoff(const float* __restrict__ Cm, const float* __restrict__ ws,
            float* __restrict__ out)
{
    __shared__ float Cs[64][68];
    __shared__ float ST[64][68];   // ST[n][p] = state[p][n]
    __shared__ float dout[64];
    const int t = threadIdx.x;
    const int sid = blockIdx.x;
    const int b = sid >> 9;
    const int c = (sid >> 4) & 31;
    const int h = sid & 15;
    const size_t rowbase = ((size_t)(b * LSEQ + c * 64) * NHEAD + h) * 64;
    const int rstride = NHEAD * 64;

    #pragma unroll
    for (int i = 0; i < 4; i++) {
        int fl = t + 256 * i; int row = fl >> 4; int c4 = fl & 15;
        float4 cv = ((const float4*)(Cm + rowbase + (size_t)row * rstride))[c4];
        *(float4*)&Cs[row][c4 * 4] = cv;
        float4 sv = ((const float4*)(ws + WS_CS + (size_t)sid * 4096 + (size_t)row * 64))[c4];
        ST[c4 * 4 + 0][row] = sv.x;
        ST[c4 * 4 + 1][row] = sv.y;
        ST[c4 * 4 + 2][row] = sv.z;
        ST[c4 * 4 + 3][row] = sv.w;
    }
    if (t < 64) dout[t] = expf(ws[WS_CA + (size_t)sid * 64 + t]);
    __syncthreads();

    const int l  = t >> 2;
    const int pb = (t & 3) * 16;
    float4 acc[4];
    #pragma unroll
    for (int i = 0; i < 4; i++) acc[i] = make_float4(0.f, 0.f, 0.f, 0.f);
    for (int n = 0; n < 64; n++) {
        float cv = Cs[l][n];
        #pragma unroll
        for (int i = 0; i < 4; i++) {
            float4 sv = *(const float4*)&ST[n][pb + 4 * i];
            acc[i].x += cv * sv.x; acc[i].y += cv * sv.y;
            acc[i].z += cv * sv.z; acc[i].w += cv * sv.w;
        }
    }
    const float sc = dout[l];
    const size_t o = rowbase + (size_t)l * rstride + pb;
    #pragma unroll
    for (int i = 0; i < 4; i++) {
        float4 yd = ((const float4*)(ws + WS_YD + o))[i];
        float4 yw = ((const float4*)(out + o))[i];
        float4 res;
        res.x = yd.x + sc * acc[i].x + yw.x;
        res.y = yd.y + sc * acc[i].y + yw.y;
        res.z = yd.z + sc * acc[i].z + yw.z;
        res.w = yd.w + sc * acc[i].w + yw.w;
        ((float4*)(out + o))[i] = res;
    }
}

extern "C" void kernel_launch(void* const* d_in, const int* in_sizes, int n_in,
                              void* d_out, int out_size, void* d_ws, size_t ws_size,
                              hipStream_t stream)
{
    const float* X  = (const float*)d_in[0];
    const float* A  = (const float*)d_in[1];
    const float* Bm = (const float*)d_in[2];
    const float* Cm = (const float*)d_in[3];
    const float* r  = (const float*)d_in[4];
    const float* k  = (const float*)d_in[5];
    const float* v  = (const float*)d_in[6];
    const float* w  = (const float*)d_in[7];
    const float* bo = (const float*)d_in[8];
    float* ws = (float*)d_ws;
    float* out = (float*)d_out;

    hipLaunchKernelGGL(k_fused, dim3(WKV_NB + SSD_NB), dim3(256), 0, stream,
                       X, A, Bm, Cm, r, k, v, w, bo, ws, out);
    hipLaunchKernelGGL(k_scan, dim3(32),     dim3(256), 0, stream, ws);
    hipLaunchKernelGGL(k_yoff, dim3(SSD_NB), dim3(256), 0, stream, Cm, ws, out);
}